// Round 7
// baseline (634.854 us; speedup 1.0000x reference)
//
#include <hip/hip_runtime.h>
#include <hip/hip_fp16.h>
#include <hip/hip_cooperative_groups.h>
namespace cg = cooperative_groups;

#define TPB 256
#define CAP 8192           // slack entries per 256-node bucket (avg fill ~4082)
#define CAPSH 13           // log2(CAP)
#define SCATTER_BLOCKS 256 // P1 virtual blocks (same work split as R5)

// One persistent cooperative kernel. Buckets: 256 nodes each (dst>>8);
// bucket b owns pairs[b*CAP..) and csr[b*CAP..) -> no cross-bucket scan.
// ALL phases are grid-stride safe: any co-resident grid >= 1 block works.

__device__ __forceinline__ int ld_idx(const void* p, long long i, int is64) {
    return is64 ? (int)((const long long*)p)[i] : ((const int*)p)[i];
}

__device__ __forceinline__ float4 h4_to_f4(ushort4 v) {
    float4 r;
    r.x = __half2float(__ushort_as_half(v.x));
    r.y = __half2float(__ushort_as_half(v.y));
    r.z = __half2float(__ushort_as_half(v.z));
    r.w = __half2float(__ushort_as_half(v.w));
    return r;
}

__device__ __forceinline__ ushort4 f4_to_h4(float4 v) {
    ushort4 r;
    r.x = __half_as_ushort(__float2half_rn(v.x));
    r.y = __half_as_ushort(__float2half_rn(v.y));
    r.z = __half_as_ushort(__float2half_rn(v.z));
    r.w = __half_as_ushort(__float2half_rn(v.w));
    return r;
}

// Cooperative gather (fp16 rows): 16 lanes batch-load 16 CSR indices in one
// coalesced read, broadcast via __shfl, then issue up to 16 INDEPENDENT 8B
// row-chunk loads (MLP ~16, no serial idx->row dependent chain).
__device__ __forceinline__ float4 gather_rows(const ushort4* __restrict__ y4,
                                              const int* __restrict__ csr,
                                              int start, int cnt, int c,
                                              float4 acc) {
    const int base = threadIdx.x & 48;           // group base lane within wave
    int j = 0;
    while (j + 16 <= cnt) {
        int idx = csr[start + j + c];
        #pragma unroll
        for (int k = 0; k < 16; ++k) {
            int s = __shfl(idx, base + k);
            float4 v = h4_to_f4(y4[s * 16 + c]);
            acc.x += v.x; acc.y += v.y; acc.z += v.z; acc.w += v.w;
        }
        j += 16;
    }
    int rem = cnt - j;                           // 0..15, group-uniform
    if (rem > 0) {
        int idx = (c < rem) ? csr[start + j + c] : 0;
        #pragma unroll
        for (int k = 0; k < 15; ++k) {
            if (k < rem) {
                int s = __shfl(idx, base + k);
                float4 v = h4_to_f4(y4[s * 16 + c]);
                acc.x += v.x; acc.y += v.y; acc.z += v.z; acc.w += v.w;
            }
        }
    }
    return acc;
}

__global__ __launch_bounds__(TPB, 4) void gcn_all(
    const void* ei, long long E, int N, int nb, int nGroups,
    const float* __restrict__ x,
    const float* __restrict__ W0, const float* __restrict__ b0,
    const float* __restrict__ W1, const float* __restrict__ b1,
    const float* __restrict__ W2, const float* __restrict__ b2,
    const float* __restrict__ Wl, const float* __restrict__ bl,
    int* gcur, int* deg, float* dis, int* offsets,
    int* pairs, int* csr,
    ushort4* ybA, ushort4* ybB, float* out)
{
    cg::grid_group grid = cg::this_grid();
    __shared__ float Ws[64 * 64];                // 16 KB, reused every phase
    __shared__ float hs[16][68];                 // +4 pad kills bank conflicts
    __shared__ int s_is64;
    const int t = threadIdx.x;
    const int ni = t >> 4, c = t & 15;

    // --- P0: per-block dtype detect + gcur init (block 0) ---
    if (t < 64) {
        const unsigned int* w = (const unsigned int*)ei;
        unsigned long long m = __ballot(w[2 * t + 1] != 0u);
        if (t == 0) s_is64 = (m == 0ull) ? 1 : 0;    // 1 => int64
    }
    if (blockIdx.x == 0) gcur[t] = t << CAPSH;
    __syncthreads();
    const int is64 = s_is64;
    grid.sync();

    // --- P1: scatter packed (src<<8 | dst&255) into bucket slack regions ---
    {
        int* cnt  = (int*)Ws;
        int* cur2 = cnt + 256;
        long long chunk = (E + SCATTER_BLOCKS - 1) / SCATTER_BLOCKS;
        for (int vb = blockIdx.x; vb < SCATTER_BLOCKS; vb += gridDim.x) {
            cnt[t] = 0;
            __syncthreads();
            long long s0 = (long long)vb * chunk;
            long long s1 = (s0 + chunk < E) ? s0 + chunk : E;
            for (long long e = s0 + t; e < s1; e += TPB)
                atomicAdd(&cnt[ld_idx(ei, E + e, is64) >> 8], 1);
            __syncthreads();
            if (cnt[t]) cur2[t] = atomicAdd(&gcur[t], cnt[t]);
            __syncthreads();
            for (long long e = s0 + t; e < s1; e += TPB) {
                int sv = ld_idx(ei, e, is64);
                int d  = ld_idx(ei, E + e, is64);
                int pos = atomicAdd(&cur2[d >> 8], 1);
                pairs[pos] = (sv << 8) | (d & 255);
            }
            __syncthreads();                     // LDS reused next vb
        }
    }
    grid.sync();

    // --- P2: per-bucket degree count, local scan, deg/dis/offsets/csr ---
    {
        int* ldeg = (int*)Ws;
        int* ssc  = ldeg + 256;
        int* cur  = ssc + 256;
        for (int b = blockIdx.x; b < nb; b += gridDim.x) {
            int base = b << CAPSH;
            int ecnt = gcur[b] - base;
            ldeg[t] = 0;
            __syncthreads();
            for (int e = base + t; e < base + ecnt; e += TPB)
                atomicAdd(&ldeg[pairs[e] & 255], 1);
            __syncthreads();
            int dv = ldeg[t];
            ssc[t] = dv;
            __syncthreads();
            for (int off = 1; off < TPB; off <<= 1) {
                int u = 0;
                if (t >= off) u = ssc[t - off];
                __syncthreads();
                ssc[t] += u;
                __syncthreads();
            }
            int o = base + ssc[t] - dv;
            cur[t] = o;
            int node = (b << 8) + t;
            if (node < N) {
                deg[node] = dv;
                dis[node] = rsqrtf((float)(dv + 1));     // +1 self loop
                offsets[node] = o;
            }
            __syncthreads();
            for (int e = base + t; e < base + ecnt; e += TPB) {
                int p = pairs[e];
                int pos = atomicAdd(&cur[p & 255], 1);
                csr[pos] = p >> 8;
            }
            __syncthreads();                     // LDS reused next bucket
        }
    }
    grid.sync();

    // --- P3: y0 = fp16(dis * (x @ W0)), grid-strided over node groups ---
    {
        float4* Ws4 = (float4*)Ws;
        const float4* W4g = (const float4*)W0;
        #pragma unroll
        for (int i = 0; i < 4; ++i) Ws4[t + i * TPB] = W4g[t + i * TPB];
        __syncthreads();
        for (int g = blockIdx.x; g < nGroups; g += gridDim.x) {
            int node = g * 16 + ni;
            float4 h = {0.f, 0.f, 0.f, 0.f};
            float dv = 0.f;
            if (node < N) {
                h = ((const float4*)x)[node * 16 + c];
                dv = dis[node];
            }
            // hs[ni] is wave-private: lockstep + lgkmcnt, no barrier needed
            *(float4*)&hs[ni][c * 4] = h;
            float4 o = {0.f, 0.f, 0.f, 0.f};
            #pragma unroll
            for (int k = 0; k < 64; ++k) {
                float hv = hs[ni][k];
                float4 w = Ws4[k * 16 + c];
                o.x = fmaf(hv, w.x, o.x);
                o.y = fmaf(hv, w.y, o.y);
                o.z = fmaf(hv, w.z, o.z);
                o.w = fmaf(hv, w.w, o.w);
            }
            if (node < N) {
                float4 r = {o.x * dv, o.y * dv, o.z * dv, o.w * dv};
                ybA[node * 16 + c] = f4_to_h4(r);
            }
        }
    }
    grid.sync();

    // --- P4/P5: two fused agg+mm layers ---
    for (int L = 0; L < 2; ++L) {
        const ushort4* yin  = (L == 0) ? ybA : ybB;
        ushort4*       yout = (L == 0) ? ybB : ybA;
        const float*   Wv   = (L == 0) ? W1 : W2;
        const float*   bvec = (L == 0) ? b0 : b1;
        float4* Ws4 = (float4*)Ws;
        const float4* W4g = (const float4*)Wv;
        #pragma unroll
        for (int i = 0; i < 4; ++i) Ws4[t + i * TPB] = W4g[t + i * TPB];
        __syncthreads();
        for (int g = blockIdx.x; g < nGroups; g += gridDim.x) {
            int node = g * 16 + ni;
            float4 h = {0.f, 0.f, 0.f, 0.f};
            float dv = 0.f;
            if (node < N) {
                float4 acc = h4_to_f4(yin[node * 16 + c]);   // self loop
                acc = gather_rows(yin, csr, offsets[node], deg[node], c, acc);
                dv = dis[node];
                float4 bb = ((const float4*)bvec)[c];
                h.x = fmaxf(fmaf(dv, acc.x, bb.x), 0.f);
                h.y = fmaxf(fmaf(dv, acc.y, bb.y), 0.f);
                h.z = fmaxf(fmaf(dv, acc.z, bb.z), 0.f);
                h.w = fmaxf(fmaf(dv, acc.w, bb.w), 0.f);
            }
            *(float4*)&hs[ni][c * 4] = h;
            float4 o = {0.f, 0.f, 0.f, 0.f};
            #pragma unroll
            for (int k = 0; k < 64; ++k) {
                float hv = hs[ni][k];
                float4 w = Ws4[k * 16 + c];
                o.x = fmaf(hv, w.x, o.x);
                o.y = fmaf(hv, w.y, o.y);
                o.z = fmaf(hv, w.z, o.z);
                o.w = fmaf(hv, w.w, o.w);
            }
            if (node < N) {
                float4 r = {o.x * dv, o.y * dv, o.z * dv, o.w * dv};
                yout[node * 16 + c] = f4_to_h4(r);
            }
        }
        grid.sync();
    }

    // --- P6: last agg + final linear (64 -> 8) ---
    {
        if (t < 128) ((float4*)Ws)[t] = ((const float4*)Wl)[t];   // Ws[0..511]
        if (t < 8)  Ws[512 + t] = bl[t];
        __syncthreads();
        for (int g = blockIdx.x; g < nGroups; g += gridDim.x) {
            int node = g * 16 + ni;
            float4 h = {0.f, 0.f, 0.f, 0.f};
            if (node < N) {
                float4 acc = h4_to_f4(ybA[node * 16 + c]);
                acc = gather_rows(ybA, csr, offsets[node], deg[node], c, acc);
                float dv = dis[node];
                float4 bb = ((const float4*)b2)[c];
                h.x = fmaxf(fmaf(dv, acc.x, bb.x), 0.f);
                h.y = fmaxf(fmaf(dv, acc.y, bb.y), 0.f);
                h.z = fmaxf(fmaf(dv, acc.z, bb.z), 0.f);
                h.w = fmaxf(fmaf(dv, acc.w, bb.w), 0.f);
            }
            *(float4*)&hs[ni][c * 4] = h;
            if (c < 8 && node < N) {
                float acc = Ws[512 + c];
                #pragma unroll
                for (int k = 0; k < 64; ++k)
                    acc = fmaf(hs[ni][k], Ws[k * 8 + c], acc);
                out[node * 8 + c] = acc;
            }
        }
    }
}

extern "C" void kernel_launch(void* const* d_in, const int* in_sizes, int n_in,
                              void* d_out, int out_size, void* d_ws, size_t ws_size,
                              hipStream_t stream) {
    const float* x  = (const float*)d_in[0];
    const void*  ei = d_in[1];
    const float* W0 = (const float*)d_in[2];
    const float* b0 = (const float*)d_in[3];
    const float* W1 = (const float*)d_in[4];
    const float* b1 = (const float*)d_in[5];
    const float* W2 = (const float*)d_in[6];
    const float* b2 = (const float*)d_in[7];
    const float* Wl = (const float*)d_in[8];
    const float* bl = (const float*)d_in[9];

    long long E = in_sizes[1] / 2;                       // 800000
    const int dh = in_sizes[3];                          // 64
    const int din = in_sizes[2] / dh;                    // 64
    int N = in_sizes[0] / din;                           // 50000
    int nb = (N + 255) >> 8;                             // 196 buckets
    int nGroups = (N + 15) / 16;                         // 3125

    // Workspace carve (256-aligned): ~27 MB total
    char* ws = (char*)d_ws;
    size_t off = 0;
    auto alloc = [&](size_t bytes) -> char* {
        char* r = ws + off;
        off += (bytes + 255) & ~(size_t)255;
        return r;
    };
    int*     gcur    = (int*)    alloc(1024);
    int*     deg     = (int*)    alloc((size_t)N * 4);
    int*     offsets = (int*)    alloc((size_t)N * 4);
    float*   dis     = (float*)  alloc((size_t)N * 4);
    int*     pairs   = (int*)    alloc((size_t)nb * CAP * 4);   // 6.4 MB slack
    int*     csr     = (int*)    alloc((size_t)nb * CAP * 4);   // 6.4 MB slack
    ushort4* ybA     = (ushort4*)alloc((size_t)N * 64 * 2);     // fp16 rows
    ushort4* ybB     = (ushort4*)alloc((size_t)N * 64 * 2);
    float*   outp    = (float*)d_out;

    // Query true co-residency (pure driver queries: graph-capture safe).
    int occ = 0, numCU = 256;
    hipOccupancyMaxActiveBlocksPerMultiprocessor(&occ, (const void*)gcn_all,
                                                 TPB, 0);
    hipDeviceGetAttribute(&numCU, hipDeviceAttributeMultiprocessorCount, 0);
    if (occ < 1) occ = 1;
    long long g = (long long)occ * numCU;
    int grid = (g > 1024) ? 1024 : (int)g;

    void* args[] = {
        (void*)&ei, (void*)&E, (void*)&N, (void*)&nb, (void*)&nGroups,
        (void*)&x,
        (void*)&W0, (void*)&b0, (void*)&W1, (void*)&b1,
        (void*)&W2, (void*)&b2, (void*)&Wl, (void*)&bl,
        (void*)&gcur, (void*)&deg, (void*)&dis, (void*)&offsets,
        (void*)&pairs, (void*)&csr, (void*)&ybA, (void*)&ybB, (void*)&outp
    };
    hipLaunchCooperativeKernel((const void*)gcn_all, dim3(grid), dim3(TPB),
                               args, 0, stream);
}

// Round 8
// 238.493 us; speedup vs baseline: 2.6619x; 2.6619x over previous
//
#include <hip/hip_runtime.h>
#include <hip/hip_fp16.h>

#define TPB 256
#define CAP 8192           // slack entries per 256-node bucket (avg fill ~4082)
#define CAPSH 13           // log2(CAP)

// Buckets: 256 nodes each (dst>>8). N=50000 -> nb=196 (must be <=256).
// Bucket b owns pairs[b*CAP..) and csr[b*CAP..) -> no cross-bucket scan.
// meta[v] = { (offset<<10) | deg, bitcast(dis) }: one 8-B load per node.

__device__ __forceinline__ int ld_idx(const void* p, long long i, int is64) {
    return is64 ? (int)((const long long*)p)[i] : ((const int*)p)[i];
}

// Single block: edge-dtype detection + gcur[b] = b*CAP.
// int64 edge_index => all odd 32-bit words of first 64 entries are zero.
__global__ void init_all(const unsigned int* w, int* flag, int* gcur) {
    int t = threadIdx.x;
    gcur[t] = t << CAPSH;
    if (t < 64) {
        unsigned int v = w[2 * t + 1];
        unsigned long long m = __ballot(v != 0u);
        if (t == 0) *flag = (m == 0ull) ? 1 : 0;   // 1 => int64
    }
}

// ---------------------------------------------------------------------------
// Scatter packed (src<<8 | dst&255) into per-bucket slack regions. Each block
// counts its chunk's bucket histogram in LDS, reserves one contiguous range
// per non-empty bucket (1 global atomic each, ~50k total), then scatters as
// contiguous runs.
// ---------------------------------------------------------------------------
__global__ __launch_bounds__(TPB) void p3_scatter(const void* ei, long long E,
                                                  const int* flag, int* gcur,
                                                  int* pairs) {
    __shared__ int cnt[TPB];
    __shared__ int cur2[TPB];
    int t = threadIdx.x;
    cnt[t] = 0;
    __syncthreads();
    int is64 = *flag;
    long long chunk = (E + gridDim.x - 1) / gridDim.x;
    long long s0 = (long long)blockIdx.x * chunk;
    long long s1 = (s0 + chunk < E) ? s0 + chunk : E;
    for (long long e = s0 + t; e < s1; e += TPB) {
        int d = ld_idx(ei, E + e, is64);
        atomicAdd(&cnt[d >> 8], 1);
    }
    __syncthreads();
    if (cnt[t]) cur2[t] = atomicAdd(&gcur[t], cnt[t]);
    __syncthreads();
    for (long long e = s0 + t; e < s1; e += TPB) {
        int sv = ld_idx(ei, e, is64);
        int d  = ld_idx(ei, E + e, is64);
        int pos = atomicAdd(&cur2[d >> 8], 1);
        pairs[pos] = (sv << 8) | (d & 255);
    }
}

// fp16 row helpers: rows are 64 halves = 128 B = 16 x ushort4.
__device__ __forceinline__ float4 h4_to_f4(ushort4 v) {
    float4 r;
    r.x = __half2float(__ushort_as_half(v.x));
    r.y = __half2float(__ushort_as_half(v.y));
    r.z = __half2float(__ushort_as_half(v.z));
    r.w = __half2float(__ushort_as_half(v.w));
    return r;
}

__device__ __forceinline__ ushort4 f4_to_h4(float4 v) {
    ushort4 r;
    r.x = __half_as_ushort(__float2half_rn(v.x));
    r.y = __half_as_ushort(__float2half_rn(v.y));
    r.z = __half_as_ushort(__float2half_rn(v.z));
    r.w = __half_as_ushort(__float2half_rn(v.w));
    return r;
}

// ---------------------------------------------------------------------------
// One block per bucket: (a) degree count from bucket-local pairs (LDS
// atomics), 256-wide LDS scan -> meta/csr (all bucket-local, written once);
// (b) then the SAME block computes y0 = fp16(dis * (x @ W0)) for its own
// 256 nodes, with W0 loaded into the (reused) LDS after a barrier.
// ---------------------------------------------------------------------------
__global__ __launch_bounds__(TPB) void p4_fill_mm(const int* __restrict__ pairs,
                                                  const int* __restrict__ gcur,
                                                  const float* __restrict__ x,
                                                  const float* __restrict__ W0,
                                                  int2* __restrict__ meta,
                                                  int* __restrict__ csr,
                                                  ushort4* __restrict__ ybA,
                                                  int N) {
    __shared__ float Ws[64 * 64];                // int scratch, then W0
    __shared__ float hs[16][68];
    __shared__ float fdis[256];
    int* ldeg = (int*)Ws;
    int* ssc  = ldeg + 256;
    int* cur  = ssc + 256;
    int t = threadIdx.x;
    int b = blockIdx.x;
    int base = b << CAPSH;
    int ecnt = gcur[b] - base;                   // edges in this bucket
    ldeg[t] = 0;
    __syncthreads();
    for (int e = base + t; e < base + ecnt; e += TPB)
        atomicAdd(&ldeg[pairs[e] & 255], 1);
    __syncthreads();
    int dv = ldeg[t];
    ssc[t] = dv;
    __syncthreads();
    for (int off = 1; off < TPB; off <<= 1) {
        int u = 0;
        if (t >= off) u = ssc[t - off];
        __syncthreads();
        ssc[t] += u;
        __syncthreads();
    }
    int o = base + ssc[t] - dv;                  // absolute exclusive offset
    cur[t] = o;
    float dd = rsqrtf((float)(dv + 1));          // +1 self loop
    fdis[t] = dd;
    int node = (b << 8) + t;
    if (node < N)
        meta[node] = make_int2((o << 10) | dv, __float_as_int(dd));
    __syncthreads();
    for (int e = base + t; e < base + ecnt; e += TPB) {
        int p = pairs[e];
        int pos = atomicAdd(&cur[p & 255], 1);
        csr[pos] = p >> 8;
    }
    __syncthreads();                             // int scratch dead

    // --- layer-0 mm for this bucket's 256 nodes ---
    float4* Ws4 = (float4*)Ws;
    const float4* W4g = (const float4*)W0;
    #pragma unroll
    for (int i = 0; i < 4; ++i) Ws4[t + i * TPB] = W4g[t + i * TPB];
    __syncthreads();
    int ni = t >> 4, c = t & 15;
    for (int p = 0; p < 16; ++p) {
        int nd = (b << 8) + p * 16 + ni;
        float4 h = {0.f, 0.f, 0.f, 0.f};
        if (nd < N) h = ((const float4*)x)[nd * 16 + c];
        // hs[ni] is wave-private: lockstep + lgkmcnt, no barrier needed
        *(float4*)&hs[ni][c * 4] = h;
        float4 oacc = {0.f, 0.f, 0.f, 0.f};
        #pragma unroll
        for (int k = 0; k < 64; ++k) {
            float hv = hs[ni][k];
            float4 w = Ws4[k * 16 + c];
            oacc.x = fmaf(hv, w.x, oacc.x);
            oacc.y = fmaf(hv, w.y, oacc.y);
            oacc.z = fmaf(hv, w.z, oacc.z);
            oacc.w = fmaf(hv, w.w, oacc.w);
        }
        if (nd < N) {
            float dvv = fdis[p * 16 + ni];
            float4 r = {oacc.x * dvv, oacc.y * dvv, oacc.z * dvv, oacc.w * dvv};
            ybA[nd * 16 + c] = f4_to_h4(r);
        }
    }
}

// ---------------------------------------------------------------------------
// Cooperative gather (fp16 rows): 16 lanes batch-load 16 CSR indices in one
// coalesced read, broadcast via __shfl, then issue up to 16 INDEPENDENT 8B
// row-chunk loads (MLP ~16, no serial idx->row dependent chain).
// ---------------------------------------------------------------------------
__device__ __forceinline__ float4 gather_rows(const ushort4* __restrict__ y4,
                                              const int* __restrict__ csr,
                                              int start, int cnt, int c,
                                              float4 acc) {
    const int base = threadIdx.x & 48;           // group base lane within wave
    int j = 0;
    while (j + 16 <= cnt) {
        int idx = csr[start + j + c];
        #pragma unroll
        for (int k = 0; k < 16; ++k) {
            int s = __shfl(idx, base + k);
            float4 v = h4_to_f4(y4[s * 16 + c]);
            acc.x += v.x; acc.y += v.y; acc.z += v.z; acc.w += v.w;
        }
        j += 16;
    }
    int rem = cnt - j;                           // 0..15, group-uniform
    if (rem > 0) {
        int idx = (c < rem) ? csr[start + j + c] : 0;
        #pragma unroll
        for (int k = 0; k < 15; ++k) {
            if (k < rem) {
                int s = __shfl(idx, base + k);
                float4 v = h4_to_f4(y4[s * 16 + c]);
                acc.x += v.x; acc.y += v.y; acc.z += v.z; acc.w += v.w;
            }
        }
    }
    return acc;
}

// ---------------------------------------------------------------------------
// Fused: h[v] = relu(dis[v]*(y[v] + sum_{in} y[src]) + b)   (fp16 gather)
//        yout[v] = fp16(dis[v] * (h[v] @ W))                (next-layer mm)
// ---------------------------------------------------------------------------
__global__ __launch_bounds__(TPB) void agg_mm(const ushort4* __restrict__ y,
                                              const int* __restrict__ csr,
                                              const int2* __restrict__ meta,
                                              const float* __restrict__ b,
                                              const float* __restrict__ W,
                                              ushort4* __restrict__ yout, int n) {
    __shared__ float Ws[64 * 64];
    __shared__ float hs[16][68];
    int t = threadIdx.x;
    const float4* W4g = (const float4*)W;
    float4* Ws4 = (float4*)Ws;
    #pragma unroll
    for (int i = 0; i < 4; ++i) Ws4[t + i * TPB] = W4g[t + i * TPB];

    int ni = t >> 4, c = t & 15;
    int node = blockIdx.x * 16 + ni;
    float4 h = {0.f, 0.f, 0.f, 0.f};
    float dv = 0.f;
    if (node < n) {
        int2 m = meta[node];
        int start = ((unsigned)m.x) >> 10;
        int cnt = m.x & 1023;
        dv = __int_as_float(m.y);
        float4 acc = h4_to_f4(y[node * 16 + c]);     // self-loop term
        acc = gather_rows(y, csr, start, cnt, c, acc);
        float4 bb = ((const float4*)b)[c];
        h.x = fmaxf(fmaf(dv, acc.x, bb.x), 0.f);
        h.y = fmaxf(fmaf(dv, acc.y, bb.y), 0.f);
        h.z = fmaxf(fmaf(dv, acc.z, bb.z), 0.f);
        h.w = fmaxf(fmaf(dv, acc.w, bb.w), 0.f);
    }
    __syncthreads();                             // Ws fully staged
    *(float4*)&hs[ni][c * 4] = h;
    float4 o = {0.f, 0.f, 0.f, 0.f};
    #pragma unroll
    for (int k = 0; k < 64; ++k) {
        float hv = hs[ni][k];
        float4 w = Ws4[k * 16 + c];
        o.x = fmaf(hv, w.x, o.x);
        o.y = fmaf(hv, w.y, o.y);
        o.z = fmaf(hv, w.z, o.z);
        o.w = fmaf(hv, w.w, o.w);
    }
    if (node < n) {
        float4 r = {o.x * dv, o.y * dv, o.z * dv, o.w * dv};
        yout[node * 16 + c] = f4_to_h4(r);
    }
}

// ---------------------------------------------------------------------------
// Fused last layer: h = relu(dis*(agg y)+b2); out = h @ linW + linb  (64->8)
// ---------------------------------------------------------------------------
__global__ __launch_bounds__(TPB) void agg_final(const ushort4* __restrict__ y,
                                                 const int* __restrict__ csr,
                                                 const int2* __restrict__ meta,
                                                 const float* __restrict__ b,
                                                 const float* __restrict__ Wl,
                                                 const float* __restrict__ bl,
                                                 float* __restrict__ out, int n) {
    __shared__ float Wls[64 * 8];
    __shared__ float bls[8];
    __shared__ float hs[16][68];
    int t = threadIdx.x;
    if (t < 128) ((float4*)Wls)[t] = ((const float4*)Wl)[t];
    if (t < 8) bls[t] = bl[t];

    int ni = t >> 4, c = t & 15;
    int node = blockIdx.x * 16 + ni;
    float4 h = {0.f, 0.f, 0.f, 0.f};
    if (node < n) {
        int2 m = meta[node];
        int start = ((unsigned)m.x) >> 10;
        int cnt = m.x & 1023;
        float dv = __int_as_float(m.y);
        float4 acc = h4_to_f4(y[node * 16 + c]);
        acc = gather_rows(y, csr, start, cnt, c, acc);
        float4 bb = ((const float4*)b)[c];
        h.x = fmaxf(fmaf(dv, acc.x, bb.x), 0.f);
        h.y = fmaxf(fmaf(dv, acc.y, bb.y), 0.f);
        h.z = fmaxf(fmaf(dv, acc.z, bb.z), 0.f);
        h.w = fmaxf(fmaf(dv, acc.w, bb.w), 0.f);
    }
    __syncthreads();                             // Wls/bls staged
    *(float4*)&hs[ni][c * 4] = h;
    if (c < 8 && node < n) {
        float acc = bls[c];
        #pragma unroll
        for (int k = 0; k < 64; ++k)
            acc = fmaf(hs[ni][k], Wls[k * 8 + c], acc);
        out[node * 8 + c] = acc;
    }
}

extern "C" void kernel_launch(void* const* d_in, const int* in_sizes, int n_in,
                              void* d_out, int out_size, void* d_ws, size_t ws_size,
                              hipStream_t stream) {
    const float* x  = (const float*)d_in[0];
    const void*  ei = d_in[1];
    const float* W0 = (const float*)d_in[2];
    const float* b0 = (const float*)d_in[3];
    const float* W1 = (const float*)d_in[4];
    const float* b1 = (const float*)d_in[5];
    const float* W2 = (const float*)d_in[6];
    const float* b2 = (const float*)d_in[7];
    const float* Wl = (const float*)d_in[8];
    const float* bl = (const float*)d_in[9];

    const long long E = in_sizes[1] / 2;                 // 800000
    const int dh = in_sizes[3];                          // 64
    const int din = in_sizes[2] / dh;                    // 64
    const int N = in_sizes[0] / din;                     // 50000
    const int nb = (N + 255) >> 8;                       // 196 buckets

    // Workspace carve (256-aligned): ~26.5 MB total
    char* ws = (char*)d_ws;
    size_t off = 0;
    auto alloc = [&](size_t bytes) -> char* {
        char* r = ws + off;
        off += (bytes + 255) & ~(size_t)255;
        return r;
    };
    int*     flag    = (int*)    alloc(4);
    int*     gcur    = (int*)    alloc(1024);
    int2*    meta    = (int2*)   alloc((size_t)N * 8);
    int*     pairs   = (int*)    alloc((size_t)nb * CAP * 4);   // 6.4 MB slack
    int*     csr     = (int*)    alloc((size_t)nb * CAP * 4);   // 6.4 MB slack
    ushort4* ybA     = (ushort4*)alloc((size_t)N * 64 * 2);     // fp16 rows
    ushort4* ybB     = (ushort4*)alloc((size_t)N * 64 * 2);

    // --- preprocessing + layer-0 mm: 3 kernels ---
    init_all<<<1, TPB, 0, stream>>>((const unsigned int*)ei, flag, gcur);
    p3_scatter<<<256, TPB, 0, stream>>>(ei, E, flag, gcur, pairs);
    p4_fill_mm<<<nb, TPB, 0, stream>>>(pairs, gcur, x, W0, meta, csr, ybA, N);

    // --- fused layers ---
    const int gL = (N + 15) / 16;                        // 3125
    agg_mm<<<gL, TPB, 0, stream>>>(ybA, csr, meta, b0, W1, ybB, N);
    agg_mm<<<gL, TPB, 0, stream>>>(ybB, csr, meta, b1, W2, ybA, N);
    agg_final<<<gL, TPB, 0, stream>>>(ybA, csr, meta, b2, Wl, bl,
                                      (float*)d_out, N);
}